// Round 1
// 875.570 us; speedup vs baseline: 25.1766x; 25.1766x over previous
//
#include <hip/hip_runtime.h>

// XTAttention — ROUND 4: full bf16-MFMA rewrite.
// B=128,N=128,D=1024,H=8,HD=128. Pipeline:
//   detect dtype -> cast W^T bf16 (8 mats) -> per chunk:
//   cast A bf16 -> proj GEMM (MFMA, k/v streams stored per-head transposed)
//   -> attn (MFMA sim + in-reg wave-parallel softmax + MFMA PV)
//   -> final GEMM (MFMA) + bias, out dtype per flag.
// GEMM structure = m97-style 128x128 tile, 4 waves, BK=32,
// global_load_lds width=16, ds_read_b128 fragments, mfma_f32_16x16x32_bf16.

typedef unsigned short u16;
typedef __attribute__((ext_vector_type(8))) short bf16x8;  // 8 bf16, 4 VGPR
typedef __attribute__((ext_vector_type(4))) short bf16x4;  // 4 bf16, 2 VGPR
typedef __attribute__((ext_vector_type(4))) float f32x4;

__device__ __forceinline__ float bf2f(u16 x) {
  union { unsigned u; float f; } v;
  v.u = ((unsigned)x) << 16;
  return v.f;
}

__device__ __forceinline__ u16 f2bf(float f) {
  union { float f; unsigned u; } v;
  v.f = f;
  unsigned r = v.u + 0x7fffu + ((v.u >> 16) & 1u);  // RTNE
  return (u16)(r >> 16);
}

__device__ __forceinline__ float ldv(const void* p, size_t i, int f32) {
  return f32 ? ((const float*)p)[i] : bf2f(((const u16*)p)[i]);
}

__device__ __forceinline__ f32x4 MFMA(bf16x8 a, bf16x8 b, f32x4 c) {
  return __builtin_amdgcn_mfma_f32_16x16x32_bf16(a, b, c, 0, 0, 0);
}

#define GLDS16(gp, lp)                                               \
  __builtin_amdgcn_global_load_lds(                                  \
      (const __attribute__((address_space(1))) unsigned int*)(gp),   \
      (__attribute__((address_space(3))) unsigned int*)(lp), 16, 0, 0)

// ---------------------------------------------------------------------------
// Dtype detection (unchanged from round 3; inputs proved f32 there).
// ---------------------------------------------------------------------------
__global__ void detect_dtype(const void* words, int* flag) {
  __shared__ int cnt;
  if (threadIdx.x == 0) cnt = 0;
  __syncthreads();
  const u16* w = (const u16*)words;
  int local = 0;
  for (int i = threadIdx.x; i < 2048; i += 256) {
    const u16 v = w[2 * i];
    const int e = (v >> 7) & 0xFF;
    if (v == 0 || (e >= 0x60 && e <= 0x8F)) local++;
  }
  atomicAdd(&cnt, local);
  __syncthreads();
  if (threadIdx.x == 0) *flag = (cnt >= 1434) ? 0 : 1;  // 1 = f32
}

// ---------------------------------------------------------------------------
// Cast + transpose the 8 weight matrices: WT[p][n][k] = W[p][k][n], bf16.
// grid (32,32,8), 256 thr.
// ---------------------------------------------------------------------------
__global__ __launch_bounds__(256) void cast_w(
    const void* w0, const void* w1, const void* w2, const void* w3,
    const void* w4, const void* w5, const void* w6, const void* w7,
    u16* __restrict__ WT, const int* __restrict__ flag) {
  __shared__ float t[32][33];
  const int f32 = *flag;
  const int p = blockIdx.z;
  const void* W;
  switch (p) {
    case 0: W = w0; break; case 1: W = w1; break; case 2: W = w2; break;
    case 3: W = w3; break; case 4: W = w4; break; case 5: W = w5; break;
    case 6: W = w6; break; default: W = w7; break;
  }
  const int k0 = blockIdx.y * 32, n0 = blockIdx.x * 32;
  const int tx = threadIdx.x & 31, ry = threadIdx.x >> 5;
  for (int r = ry; r < 32; r += 8)
    t[r][tx] = ldv(W, (size_t)(k0 + r) * 1024 + n0 + tx, f32);
  __syncthreads();
  u16* dst = WT + (size_t)p * 1048576ull;
  for (int r = ry; r < 32; r += 8)
    dst[(size_t)(n0 + r) * 1024 + k0 + tx] = f2bf(t[tx][r]);
}

// ---------------------------------------------------------------------------
// Cast activations (chunk rows) to bf16. grid (512,1,3).
// ---------------------------------------------------------------------------
__global__ __launch_bounds__(256) void cast_a(
    const void* x0, const void* x1, const void* x2, u16* __restrict__ Abf,
    int b0, int chb, const int* __restrict__ flag) {
  const int f32 = *flag;
  const int t = blockIdx.z;
  const void* src = (t == 0) ? x0 : ((t == 1) ? x1 : x2);
  u16* dst = Abf + (size_t)t * (size_t)chb * 131072ull;
  const size_t n4 = (size_t)chb * 32768ull;          // groups of 4 elems
  const size_t off = (size_t)b0 * 131072ull;         // src elem offset
  const size_t stride = (size_t)gridDim.x * 256ull;
  if (f32) {
    const float4* s = (const float4*)src + off / 4;
    for (size_t i = (size_t)blockIdx.x * 256 + threadIdx.x; i < n4; i += stride) {
      const float4 v = s[i];
      bf16x4 o = { (short)f2bf(v.x), (short)f2bf(v.y),
                   (short)f2bf(v.z), (short)f2bf(v.w) };
      *(bf16x4*)&dst[i * 4] = o;
    }
  } else {
    const bf16x4* s = (const bf16x4*)((const u16*)src + off);
    for (size_t i = (size_t)blockIdx.x * 256 + threadIdx.x; i < n4; i += stride)
      ((bf16x4*)dst)[i] = s[i];
  }
}

// ---------------------------------------------------------------------------
// 7 projections, MFMA. 128x128 tile/block, 4 waves (2x2), BK=32.
// grid (8, CHB, 7): x = output col tile (== head), y = b_local.
// Streams 1,2,4,6 (k_w, v_w, k_p, k_c) stored per-head transposed:
//   T[(b*8+h)*128 + d][j]   (j = seq index)
// ---------------------------------------------------------------------------
__global__ __launch_bounds__(256) void proj_mfma(
    const u16* __restrict__ Abf, const u16* __restrict__ WT,
    u16* __restrict__ P, int chb) {
  __shared__ u16 lsA[128 * 32];
  __shared__ u16 lsB[128 * 32];
  const int p = blockIdx.z;
  const int asel = (p < 3) ? 0 : ((p < 5) ? 1 : 2);
  const u16* A = Abf + (size_t)asel * (size_t)chb * 131072ull;
  const u16* W = WT + (size_t)p * 1048576ull;
  u16* C = P + (size_t)p * (size_t)chb * 131072ull;
  const int tr = (p == 1) | (p == 2) | (p == 4) | (p == 6);
  const int tn = blockIdx.x * 128;
  const int tm = blockIdx.y * 128;
  const int w = threadIdx.x >> 6, l = threadIdx.x & 63;
  const int wm = w >> 1, wn = w & 1;
  const int srow = w * 32 + (l >> 2);  // staging row (+c*16)
  const int skl = (l & 3) * 8;         // staging k offset (elems)

  f32x4 acc[4][4] = {};
  for (int kt = 0; kt < 1024; kt += 32) {
    #pragma unroll
    for (int c = 0; c < 2; ++c) {
      GLDS16(&A[(size_t)(tm + srow + c * 16) * 1024 + kt + skl],
             &lsA[(w * 32 + c * 16) * 32]);
      GLDS16(&W[(size_t)(tn + srow + c * 16) * 1024 + kt + skl],
             &lsB[(w * 32 + c * 16) * 32]);
    }
    __syncthreads();
    bf16x8 af[4], bfr[4];
    #pragma unroll
    for (int m = 0; m < 4; ++m)
      af[m] = *(const bf16x8*)&lsA[(wm * 64 + m * 16 + (l & 15)) * 32 + (l >> 4) * 8];
    #pragma unroll
    for (int n = 0; n < 4; ++n)
      bfr[n] = *(const bf16x8*)&lsB[(wn * 64 + n * 16 + (l & 15)) * 32 + (l >> 4) * 8];
    #pragma unroll
    for (int m = 0; m < 4; ++m)
      #pragma unroll
      for (int n = 0; n < 4; ++n)
        acc[m][n] = MFMA(af[m], bfr[n], acc[m][n]);
    __syncthreads();
  }

  if (!tr) {
    #pragma unroll
    for (int m = 0; m < 4; ++m)
      #pragma unroll
      for (int n = 0; n < 4; ++n)
        #pragma unroll
        for (int r = 0; r < 4; ++r) {
          const int row = tm + wm * 64 + m * 16 + (l >> 4) * 4 + r;
          const int col = tn + wn * 64 + n * 16 + (l & 15);
          C[(size_t)row * 1024 + col] = f2bf(acc[m][n][r]);
        }
  } else {
    const size_t tb = ((size_t)blockIdx.y * 8 + blockIdx.x) * 16384ull;
    #pragma unroll
    for (int m = 0; m < 4; ++m)
      #pragma unroll
      for (int n = 0; n < 4; ++n) {
        const int d = wn * 64 + n * 16 + (l & 15);
        const int j0 = wm * 64 + m * 16 + (l >> 4) * 4;
        bf16x4 v = { (short)f2bf(acc[m][n][0]), (short)f2bf(acc[m][n][1]),
                     (short)f2bf(acc[m][n][2]), (short)f2bf(acc[m][n][3]) };
        *(bf16x4*)&C[tb + (size_t)d * 128 + j0] = v;
      }
  }
}

// ---------------------------------------------------------------------------
// Attention: one block per (b_local, h), 4 waves x 32 rows.
// sim = sum_t Q_t @ K_t (MFMA, A-frags direct from global — layout matches),
// softmax fully in-register (16-lane shfl reduces), P via swizzled LDS,
// PV = P @ V (V pre-transposed). Output merged[b,i,h*128+d] bf16.
// ---------------------------------------------------------------------------
__global__ __launch_bounds__(256) void attn_mfma(
    const u16* __restrict__ P, int chb, u16* __restrict__ merged) {
  __shared__ u16 pl[16384];  // 128x128 bf16, row-swizzled
  const int h = blockIdx.x, b = blockIdx.y;
  const int w = threadIdx.x >> 6, l = threadIdx.x & 63;
  const size_t MS = (size_t)chb * 131072ull;
  const u16* const Qs[3] = { P, P + 3 * MS, P + 5 * MS };      // q_w,q_p,q_c
  const u16* const Ks[3] = { P + 1 * MS, P + 4 * MS, P + 6 * MS };  // kT
  const u16* V = P + 2 * MS;                                   // vT
  const size_t qb = (size_t)b * 131072ull + (size_t)h * 128;   // +i*1024+j
  const size_t kb = ((size_t)b * 8 + h) * 16384ull;            // +d*128+j

  // ---- sim = sum of 3 streams, rows w*32..w*32+31, all 128 cols ----
  f32x4 acc[2][8] = {};
  #pragma unroll
  for (int kt = 0; kt < 128; kt += 32) {
    #pragma unroll
    for (int t = 0; t < 3; ++t) {
      bf16x8 a[2];
      #pragma unroll
      for (int m = 0; m < 2; ++m)
        a[m] = *(const bf16x8*)&Qs[t][qb + (size_t)(w * 32 + m * 16 + (l & 15)) * 1024
                                       + kt + (l >> 4) * 8];
      #pragma unroll
      for (int n = 0; n < 8; ++n) {
        const bf16x8 bb = *(const bf16x8*)&Ks[t][kb + (size_t)(n * 16 + (l & 15)) * 128
                                                 + kt + (l >> 4) * 8];
        acc[0][n] = MFMA(a[0], bb, acc[0][n]);
        acc[1][n] = MFMA(a[1], bb, acc[1][n]);
      }
    }
  }

  // ---- softmax over cols, in-register. Row of (m,r) lives on the 16 lanes
  //      sharing (l>>4); masks 1,2,4,8 stay inside that group. ----
  const float SC = 0.08838834764831845f;
  #pragma unroll
  for (int m = 0; m < 2; ++m)
    #pragma unroll
    for (int r = 0; r < 4; ++r) {
      float mx = -3.0e38f;
      #pragma unroll
      for (int n = 0; n < 8; ++n) {
        acc[m][n][r] *= SC;
        mx = fmaxf(mx, acc[m][n][r]);
      }
      #pragma unroll
      for (int s = 1; s < 16; s <<= 1) mx = fmaxf(mx, __shfl_xor(mx, s));
      float sm = 0.f;
      #pragma unroll
      for (int n = 0; n < 8; ++n) {
        const float e = __expf(acc[m][n][r] - mx);
        acc[m][n][r] = e;
        sm += e;
      }
      #pragma unroll
      for (int s = 1; s < 16; s <<= 1) sm += __shfl_xor(sm, s);
      const float inv = 1.f / sm;
      #pragma unroll
      for (int n = 0; n < 8; ++n) acc[m][n][r] *= inv;
    }

  // ---- write P tile to LDS, XOR-swizzled rows (kills 16-way ds_read conflict)
  #pragma unroll
  for (int m = 0; m < 2; ++m)
    #pragma unroll
    for (int n = 0; n < 8; ++n)
      #pragma unroll
      for (int r = 0; r < 4; ++r) {
        const int row = w * 32 + m * 16 + (l >> 4) * 4 + r;
        const int col = n * 16 + (l & 15);
        const int byte = (row * 256 + col * 2) ^ ((row & 7) << 4);
        *(u16*)((char*)pl + byte) = f2bf(acc[m][n][r]);
      }
  __syncthreads();

  // ---- PV: o = P @ V ----
  f32x4 o[2][8] = {};
  #pragma unroll
  for (int kt = 0; kt < 128; kt += 32) {
    bf16x8 a[2];
    #pragma unroll
    for (int m = 0; m < 2; ++m) {
      const int row = w * 32 + m * 16 + (l & 15);
      const int byte = (row * 256 + (kt + (l >> 4) * 8) * 2) ^ ((row & 7) << 4);
      a[m] = *(const bf16x8*)((char*)pl + byte);
    }
    #pragma unroll
    for (int n = 0; n < 8; ++n) {
      const bf16x8 bb = *(const bf16x8*)&V[kb + (size_t)(n * 16 + (l & 15)) * 128
                                           + kt + (l >> 4) * 8];
      o[0][n] = MFMA(a[0], bb, o[0][n]);
      o[1][n] = MFMA(a[1], bb, o[1][n]);
    }
  }

  #pragma unroll
  for (int m = 0; m < 2; ++m)
    #pragma unroll
    for (int n = 0; n < 8; ++n)
      #pragma unroll
      for (int r = 0; r < 4; ++r) {
        const int row = w * 32 + m * 16 + (l >> 4) * 4 + r;
        const int col = n * 16 + (l & 15);
        merged[(size_t)(b * 128 + row) * 1024 + h * 128 + col] = f2bf(o[m][n][r]);
      }
}

// ---------------------------------------------------------------------------
// Final projection: out = merged @ Wo + bo. Same GEMM structure; output dtype
// follows flag. grid (8, CHB).
// ---------------------------------------------------------------------------
__global__ __launch_bounds__(256) void final_mfma(
    const u16* __restrict__ A, const u16* __restrict__ W,
    const void* __restrict__ bias, void* __restrict__ out, int b0,
    const int* __restrict__ flag) {
  __shared__ u16 lsA[128 * 32];
  __shared__ u16 lsB[128 * 32];
  const int f32 = *flag;
  const int tn = blockIdx.x * 128;
  const int tm = blockIdx.y * 128;
  const int w = threadIdx.x >> 6, l = threadIdx.x & 63;
  const int wm = w >> 1, wn = w & 1;
  const int srow = w * 32 + (l >> 2);
  const int skl = (l & 3) * 8;

  f32x4 acc[4][4] = {};
  for (int kt = 0; kt < 1024; kt += 32) {
    #pragma unroll
    for (int c = 0; c < 2; ++c) {
      GLDS16(&A[(size_t)(tm + srow + c * 16) * 1024 + kt + skl],
             &lsA[(w * 32 + c * 16) * 32]);
      GLDS16(&W[(size_t)(tn + srow + c * 16) * 1024 + kt + skl],
             &lsB[(w * 32 + c * 16) * 32]);
    }
    __syncthreads();
    bf16x8 af[4], bfr[4];
    #pragma unroll
    for (int m = 0; m < 4; ++m)
      af[m] = *(const bf16x8*)&lsA[(wm * 64 + m * 16 + (l & 15)) * 32 + (l >> 4) * 8];
    #pragma unroll
    for (int n = 0; n < 4; ++n)
      bfr[n] = *(const bf16x8*)&lsB[(wn * 64 + n * 16 + (l & 15)) * 32 + (l >> 4) * 8];
    #pragma unroll
    for (int m = 0; m < 4; ++m)
      #pragma unroll
      for (int n = 0; n < 4; ++n)
        acc[m][n] = MFMA(af[m], bfr[n], acc[m][n]);
    __syncthreads();
  }

  #pragma unroll
  for (int m = 0; m < 4; ++m)
    #pragma unroll
    for (int n = 0; n < 4; ++n)
      #pragma unroll
      for (int r = 0; r < 4; ++r) {
        const int row = tm + wm * 64 + m * 16 + (l >> 4) * 4 + r;
        const int col = tn + wn * 64 + n * 16 + (l & 15);
        const float rv = acc[m][n][r] + ldv(bias, col, f32);
        const size_t g = (size_t)(b0 * 128 + row) * 1024 + col;
        if (f32) ((float*)out)[g] = rv;
        else ((u16*)out)[g] = f2bf(rv);
      }
}

// ---------------------------------------------------------------------------
extern "C" void kernel_launch(void* const* d_in, const int* in_sizes, int n_in,
                              void* d_out, int out_size, void* d_ws, size_t ws_size,
                              hipStream_t stream) {
  // d_in: 0 words, 1 position, 2 conscious, 3 Wq_w, 4 Wk_w, 5 Wv_w,
  //       6 Wq_p, 7 Wk_p, 8 Wq_c, 9 Wk_c, 10 Wo, 11 bo
  // ws: [flag 64B][WT 8*1M bf16][Abf 3*CHB*128K bf16][P 7*CHB*128K bf16]
  //     [merged CHB*128K bf16]
  const size_t fixed = 64ull + 8ull * 1048576ull * 2ull;
  int CHB = 128;
  while (CHB > 1 && fixed + 11ull * (size_t)CHB * 131072ull * 2ull > ws_size)
    CHB >>= 1;

  int* flag = (int*)d_ws;
  u16* WT = (u16*)((char*)d_ws + 64);
  u16* Abf = WT + 8ull * 1048576ull;
  u16* P = Abf + 3ull * (size_t)CHB * 131072ull;
  u16* merged = P + 7ull * (size_t)CHB * 131072ull;

  detect_dtype<<<1, 256, 0, stream>>>(d_in[0], flag);
  cast_w<<<dim3(32, 32, 8), 256, 0, stream>>>(
      d_in[3], d_in[4], d_in[5], d_in[6], d_in[7], d_in[8], d_in[9], d_in[10],
      WT, flag);

  for (int b0 = 0; b0 < 128; b0 += CHB) {
    cast_a<<<dim3(512, 1, 3), 256, 0, stream>>>(
        d_in[0], d_in[1], d_in[2], Abf, b0, CHB, flag);
    proj_mfma<<<dim3(8, CHB, 7), 256, 0, stream>>>(Abf, WT, P, CHB);
    attn_mfma<<<dim3(8, CHB), 256, 0, stream>>>(P, CHB, merged);
    final_mfma<<<dim3(8, CHB), 256, 0, stream>>>(
        merged, WT + 7ull * 1048576ull, d_in[11], d_out, b0, flag);
  }
}

// Round 2
// 834.841 us; speedup vs baseline: 26.4048x; 1.0488x over previous
//
#include <hip/hip_runtime.h>

// XTAttention — ROUND 5: proj/final GEMM tuning.
//   + T1 XCD-aware bijective block swizzle (8 col-blocks sharing an A row
//     panel now colocate on one XCD's L2; FETCH was 2.9x ideal).
//   + BK 32->64 (halves barrier-drain events; K=1024 -> 16 iters) with
//     both-sides XOR swizzle (linear gload_lds dest, pre-swizzled global
//     source col, swizzled ds_read) to keep LDS reads conflict-free.
// attn/casts unchanged from round 4 (verified).
// B=128,N=128,D=1024,H=8,HD=128.

typedef unsigned short u16;
typedef __attribute__((ext_vector_type(8))) short bf16x8;  // 8 bf16, 4 VGPR
typedef __attribute__((ext_vector_type(4))) short bf16x4;  // 4 bf16, 2 VGPR
typedef __attribute__((ext_vector_type(4))) float f32x4;

__device__ __forceinline__ float bf2f(u16 x) {
  union { unsigned u; float f; } v;
  v.u = ((unsigned)x) << 16;
  return v.f;
}

__device__ __forceinline__ u16 f2bf(float f) {
  union { float f; unsigned u; } v;
  v.f = f;
  unsigned r = v.u + 0x7fffu + ((v.u >> 16) & 1u);  // RTNE
  return (u16)(r >> 16);
}

__device__ __forceinline__ float ldv(const void* p, size_t i, int f32) {
  return f32 ? ((const float*)p)[i] : bf2f(((const u16*)p)[i]);
}

__device__ __forceinline__ f32x4 MFMA(bf16x8 a, bf16x8 b, f32x4 c) {
  return __builtin_amdgcn_mfma_f32_16x16x32_bf16(a, b, c, 0, 0, 0);
}

#define GLDS16(gp, lp)                                               \
  __builtin_amdgcn_global_load_lds(                                  \
      (const __attribute__((address_space(1))) unsigned int*)(gp),   \
      (__attribute__((address_space(3))) unsigned int*)(lp), 16, 0, 0)

// Swizzled LDS fragment read: logical (row, byte-col) of a [128][64] bf16
// tile stored with LDS[row][x] = G[row][x ^ ((row&7)<<4)] (16B granules).
__device__ __forceinline__ bf16x8 lds_frag(const u16* ls, int row, int cb) {
  const int byte = (row * 128 + cb) ^ ((row & 7) << 4);
  return *(const bf16x8*)((const char*)ls + byte);
}

// ---------------------------------------------------------------------------
// Dtype detection (inputs proved f32 in round 3; keep runtime check).
// ---------------------------------------------------------------------------
__global__ void detect_dtype(const void* words, int* flag) {
  __shared__ int cnt;
  if (threadIdx.x == 0) cnt = 0;
  __syncthreads();
  const u16* w = (const u16*)words;
  int local = 0;
  for (int i = threadIdx.x; i < 2048; i += 256) {
    const u16 v = w[2 * i];
    const int e = (v >> 7) & 0xFF;
    if (v == 0 || (e >= 0x60 && e <= 0x8F)) local++;
  }
  atomicAdd(&cnt, local);
  __syncthreads();
  if (threadIdx.x == 0) *flag = (cnt >= 1434) ? 0 : 1;  // 1 = f32
}

// ---------------------------------------------------------------------------
// Cast + transpose the 8 weight matrices: WT[p][n][k] = W[p][k][n], bf16.
// ---------------------------------------------------------------------------
__global__ __launch_bounds__(256) void cast_w(
    const void* w0, const void* w1, const void* w2, const void* w3,
    const void* w4, const void* w5, const void* w6, const void* w7,
    u16* __restrict__ WT, const int* __restrict__ flag) {
  __shared__ float t[32][33];
  const int f32 = *flag;
  const int p = blockIdx.z;
  const void* W;
  switch (p) {
    case 0: W = w0; break; case 1: W = w1; break; case 2: W = w2; break;
    case 3: W = w3; break; case 4: W = w4; break; case 5: W = w5; break;
    case 6: W = w6; break; default: W = w7; break;
  }
  const int k0 = blockIdx.y * 32, n0 = blockIdx.x * 32;
  const int tx = threadIdx.x & 31, ry = threadIdx.x >> 5;
  for (int r = ry; r < 32; r += 8)
    t[r][tx] = ldv(W, (size_t)(k0 + r) * 1024 + n0 + tx, f32);
  __syncthreads();
  u16* dst = WT + (size_t)p * 1048576ull;
  for (int r = ry; r < 32; r += 8)
    dst[(size_t)(n0 + r) * 1024 + k0 + tx] = f2bf(t[tx][r]);
}

// ---------------------------------------------------------------------------
// Cast activations (chunk rows) to bf16. grid (512,1,3).
// ---------------------------------------------------------------------------
__global__ __launch_bounds__(256) void cast_a(
    const void* x0, const void* x1, const void* x2, u16* __restrict__ Abf,
    int b0, int chb, const int* __restrict__ flag) {
  const int f32 = *flag;
  const int t = blockIdx.z;
  const void* src = (t == 0) ? x0 : ((t == 1) ? x1 : x2);
  u16* dst = Abf + (size_t)t * (size_t)chb * 131072ull;
  const size_t n4 = (size_t)chb * 32768ull;
  const size_t off = (size_t)b0 * 131072ull;
  const size_t stride = (size_t)gridDim.x * 256ull;
  if (f32) {
    const float4* s = (const float4*)src + off / 4;
    for (size_t i = (size_t)blockIdx.x * 256 + threadIdx.x; i < n4; i += stride) {
      const float4 v = s[i];
      bf16x4 o = { (short)f2bf(v.x), (short)f2bf(v.y),
                   (short)f2bf(v.z), (short)f2bf(v.w) };
      *(bf16x4*)&dst[i * 4] = o;
    }
  } else {
    const bf16x4* s = (const bf16x4*)((const u16*)src + off);
    for (size_t i = (size_t)blockIdx.x * 256 + threadIdx.x; i < n4; i += stride)
      ((bf16x4*)dst)[i] = s[i];
  }
}

// ---------------------------------------------------------------------------
// 7 projections, MFMA. 128x128 tile/block, 4 waves (2x2), BK=64.
// grid (8, CHB, 7): x = output col tile (== head), y = b_local; (x,y)
// remapped XCD-aware so col-blocks sharing an A panel share an XCD L2.
// Streams 1,2,4,6 (k_w, v_w, k_p, k_c) stored per-head transposed:
//   T[(b*8+h)*128 + d][j]
// ---------------------------------------------------------------------------
__global__ __launch_bounds__(256) void proj_mfma(
    const u16* __restrict__ Abf, const u16* __restrict__ WT,
    u16* __restrict__ P, int chb) {
  __shared__ u16 lsA[128 * 64];
  __shared__ u16 lsB[128 * 64];
  const int p = blockIdx.z;
  const int asel = (p < 3) ? 0 : ((p < 5) ? 1 : 2);
  const u16* A = Abf + (size_t)asel * (size_t)chb * 131072ull;
  const u16* W = WT + (size_t)p * 1048576ull;
  u16* C = P + (size_t)p * (size_t)chb * 131072ull;
  const int tr = (p == 1) | (p == 2) | (p == 4) | (p == 6);

  // XCD-aware bijective remap (nwg = 8*CHB, divisible by 8).
  int wg = blockIdx.y * 8 + blockIdx.x;
  const int nwg = (int)gridDim.y * 8;
  wg = (wg & 7) * (nwg >> 3) + (wg >> 3);
  const int bx = wg & 7, by = wg >> 3;

  const int tn = bx * 128;
  const int tm = by * 128;
  const int w = threadIdx.x >> 6, l = threadIdx.x & 63;
  const int wm = w >> 1, wn = w & 1;
  // Staging: 4 gload_lds per operand per wave; lane covers row lr, 16B col lc
  // (lc pre-XOR-swizzled so the linear LDS dest holds swizzled data).
  const int lr = l >> 3;                              // 0..7
  const int lc = ((l & 7) * 16) ^ (lr << 4);          // byte col, pre-swizzled
  const int fr = l & 15, fq = l >> 4;                 // fragment row/quad

  f32x4 acc[4][4] = {};
  for (int kt = 0; kt < 1024; kt += 64) {
    #pragma unroll
    for (int c = 0; c < 4; ++c) {
      GLDS16(&A[(size_t)(tm + w * 32 + c * 8 + lr) * 1024 + kt + (lc >> 1)],
             &lsA[(w * 32 + c * 8) * 64]);
      GLDS16(&W[(size_t)(tn + w * 32 + c * 8 + lr) * 1024 + kt + (lc >> 1)],
             &lsB[(w * 32 + c * 8) * 64]);
    }
    __syncthreads();
    #pragma unroll
    for (int ks = 0; ks < 2; ++ks) {
      bf16x8 af[4], bfr[4];
      const int cb = ks * 64 + fq * 16;
      #pragma unroll
      for (int m = 0; m < 4; ++m)
        af[m] = lds_frag(lsA, wm * 64 + m * 16 + fr, cb);
      #pragma unroll
      for (int n = 0; n < 4; ++n)
        bfr[n] = lds_frag(lsB, wn * 64 + n * 16 + fr, cb);
      #pragma unroll
      for (int m = 0; m < 4; ++m)
        #pragma unroll
        for (int n = 0; n < 4; ++n)
          acc[m][n] = MFMA(af[m], bfr[n], acc[m][n]);
    }
    __syncthreads();
  }

  if (!tr) {
    #pragma unroll
    for (int m = 0; m < 4; ++m)
      #pragma unroll
      for (int n = 0; n < 4; ++n)
        #pragma unroll
        for (int r = 0; r < 4; ++r) {
          const int row = tm + wm * 64 + m * 16 + fq * 4 + r;
          const int col = tn + wn * 64 + n * 16 + fr;
          C[(size_t)row * 1024 + col] = f2bf(acc[m][n][r]);
        }
  } else {
    const size_t tb = ((size_t)by * 8 + bx) * 16384ull;
    #pragma unroll
    for (int m = 0; m < 4; ++m)
      #pragma unroll
      for (int n = 0; n < 4; ++n) {
        const int d = wn * 64 + n * 16 + fr;
        const int j0 = wm * 64 + m * 16 + fq * 4;
        bf16x4 v = { (short)f2bf(acc[m][n][0]), (short)f2bf(acc[m][n][1]),
                     (short)f2bf(acc[m][n][2]), (short)f2bf(acc[m][n][3]) };
        *(bf16x4*)&C[tb + (size_t)d * 128 + j0] = v;
      }
  }
}

// ---------------------------------------------------------------------------
// Attention: one block per (b_local, h), 4 waves x 32 rows. (Unchanged.)
// ---------------------------------------------------------------------------
__global__ __launch_bounds__(256) void attn_mfma(
    const u16* __restrict__ P, int chb, u16* __restrict__ merged) {
  __shared__ u16 pl[16384];  // 128x128 bf16, row-swizzled
  const int h = blockIdx.x, b = blockIdx.y;
  const int w = threadIdx.x >> 6, l = threadIdx.x & 63;
  const size_t MS = (size_t)chb * 131072ull;
  const u16* const Qs[3] = { P, P + 3 * MS, P + 5 * MS };
  const u16* const Ks[3] = { P + 1 * MS, P + 4 * MS, P + 6 * MS };
  const u16* V = P + 2 * MS;
  const size_t qb = (size_t)b * 131072ull + (size_t)h * 128;
  const size_t kb = ((size_t)b * 8 + h) * 16384ull;

  f32x4 acc[2][8] = {};
  #pragma unroll
  for (int kt = 0; kt < 128; kt += 32) {
    #pragma unroll
    for (int t = 0; t < 3; ++t) {
      bf16x8 a[2];
      #pragma unroll
      for (int m = 0; m < 2; ++m)
        a[m] = *(const bf16x8*)&Qs[t][qb + (size_t)(w * 32 + m * 16 + (l & 15)) * 1024
                                       + kt + (l >> 4) * 8];
      #pragma unroll
      for (int n = 0; n < 8; ++n) {
        const bf16x8 bb = *(const bf16x8*)&Ks[t][kb + (size_t)(n * 16 + (l & 15)) * 128
                                                 + kt + (l >> 4) * 8];
        acc[0][n] = MFMA(a[0], bb, acc[0][n]);
        acc[1][n] = MFMA(a[1], bb, acc[1][n]);
      }
    }
  }

  const float SC = 0.08838834764831845f;
  #pragma unroll
  for (int m = 0; m < 2; ++m)
    #pragma unroll
    for (int r = 0; r < 4; ++r) {
      float mx = -3.0e38f;
      #pragma unroll
      for (int n = 0; n < 8; ++n) {
        acc[m][n][r] *= SC;
        mx = fmaxf(mx, acc[m][n][r]);
      }
      #pragma unroll
      for (int s = 1; s < 16; s <<= 1) mx = fmaxf(mx, __shfl_xor(mx, s));
      float sm = 0.f;
      #pragma unroll
      for (int n = 0; n < 8; ++n) {
        const float e = __expf(acc[m][n][r] - mx);
        acc[m][n][r] = e;
        sm += e;
      }
      #pragma unroll
      for (int s = 1; s < 16; s <<= 1) sm += __shfl_xor(sm, s);
      const float inv = 1.f / sm;
      #pragma unroll
      for (int n = 0; n < 8; ++n) acc[m][n][r] *= inv;
    }

  #pragma unroll
  for (int m = 0; m < 2; ++m)
    #pragma unroll
    for (int n = 0; n < 8; ++n)
      #pragma unroll
      for (int r = 0; r < 4; ++r) {
        const int row = w * 32 + m * 16 + (l >> 4) * 4 + r;
        const int col = n * 16 + (l & 15);
        const int byte = (row * 256 + col * 2) ^ ((row & 7) << 4);
        *(u16*)((char*)pl + byte) = f2bf(acc[m][n][r]);
      }
  __syncthreads();

  f32x4 o[2][8] = {};
  #pragma unroll
  for (int kt = 0; kt < 128; kt += 32) {
    bf16x8 a[2];
    #pragma unroll
    for (int m = 0; m < 2; ++m) {
      const int row = w * 32 + m * 16 + (l & 15);
      const int byte = (row * 256 + (kt + (l >> 4) * 8) * 2) ^ ((row & 7) << 4);
      a[m] = *(const bf16x8*)((char*)pl + byte);
    }
    #pragma unroll
    for (int n = 0; n < 8; ++n) {
      const bf16x8 bb = *(const bf16x8*)&V[kb + (size_t)(n * 16 + (l & 15)) * 128
                                           + kt + (l >> 4) * 8];
      o[0][n] = MFMA(a[0], bb, o[0][n]);
      o[1][n] = MFMA(a[1], bb, o[1][n]);
    }
  }

  #pragma unroll
  for (int m = 0; m < 2; ++m)
    #pragma unroll
    for (int n = 0; n < 8; ++n)
      #pragma unroll
      for (int r = 0; r < 4; ++r) {
        const int row = w * 32 + m * 16 + (l >> 4) * 4 + r;
        const int col = n * 16 + (l & 15);
        merged[(size_t)(b * 128 + row) * 1024 + h * 128 + col] = f2bf(o[m][n][r]);
      }
}

// ---------------------------------------------------------------------------
// Final projection: out = merged @ Wo + bo. BK=64 + swizzles like proj.
// ---------------------------------------------------------------------------
__global__ __launch_bounds__(256) void final_mfma(
    const u16* __restrict__ A, const u16* __restrict__ W,
    const void* __restrict__ bias, void* __restrict__ out, int b0,
    const int* __restrict__ flag) {
  __shared__ u16 lsA[128 * 64];
  __shared__ u16 lsB[128 * 64];
  const int f32 = *flag;

  int wg = blockIdx.y * 8 + blockIdx.x;
  const int nwg = (int)gridDim.y * 8;
  wg = (wg & 7) * (nwg >> 3) + (wg >> 3);
  const int bx = wg & 7, by = wg >> 3;

  const int tn = bx * 128;
  const int tm = by * 128;
  const int w = threadIdx.x >> 6, l = threadIdx.x & 63;
  const int wm = w >> 1, wn = w & 1;
  const int lr = l >> 3;
  const int lc = ((l & 7) * 16) ^ (lr << 4);
  const int fr = l & 15, fq = l >> 4;

  f32x4 acc[4][4] = {};
  for (int kt = 0; kt < 1024; kt += 64) {
    #pragma unroll
    for (int c = 0; c < 4; ++c) {
      GLDS16(&A[(size_t)(tm + w * 32 + c * 8 + lr) * 1024 + kt + (lc >> 1)],
             &lsA[(w * 32 + c * 8) * 64]);
      GLDS16(&W[(size_t)(tn + w * 32 + c * 8 + lr) * 1024 + kt + (lc >> 1)],
             &lsB[(w * 32 + c * 8) * 64]);
    }
    __syncthreads();
    #pragma unroll
    for (int ks = 0; ks < 2; ++ks) {
      bf16x8 af[4], bfr[4];
      const int cb = ks * 64 + fq * 16;
      #pragma unroll
      for (int m = 0; m < 4; ++m)
        af[m] = lds_frag(lsA, wm * 64 + m * 16 + fr, cb);
      #pragma unroll
      for (int n = 0; n < 4; ++n)
        bfr[n] = lds_frag(lsB, wn * 64 + n * 16 + fr, cb);
      #pragma unroll
      for (int m = 0; m < 4; ++m)
        #pragma unroll
        for (int n = 0; n < 4; ++n)
          acc[m][n] = MFMA(af[m], bfr[n], acc[m][n]);
    }
    __syncthreads();
  }

  #pragma unroll
  for (int m = 0; m < 4; ++m)
    #pragma unroll
    for (int n = 0; n < 4; ++n)
      #pragma unroll
      for (int r = 0; r < 4; ++r) {
        const int row = tm + wm * 64 + m * 16 + fq * 4 + r;
        const int col = tn + wn * 64 + n * 16 + fr;
        const float rv = acc[m][n][r] + ldv(bias, col, f32);
        const size_t g = (size_t)(b0 * 128 + row) * 1024 + col;
        if (f32) ((float*)out)[g] = rv;
        else ((u16*)out)[g] = f2bf(rv);
      }
}

// ---------------------------------------------------------------------------
extern "C" void kernel_launch(void* const* d_in, const int* in_sizes, int n_in,
                              void* d_out, int out_size, void* d_ws, size_t ws_size,
                              hipStream_t stream) {
  // d_in: 0 words, 1 position, 2 conscious, 3 Wq_w, 4 Wk_w, 5 Wv_w,
  //       6 Wq_p, 7 Wk_p, 8 Wq_c, 9 Wk_c, 10 Wo, 11 bo
  // ws: [flag 64B][WT 8*1M bf16][Abf 3*CHB*128K bf16][P 7*CHB*128K bf16]
  //     [merged CHB*128K bf16]
  const size_t fixed = 64ull + 8ull * 1048576ull * 2ull;
  int CHB = 128;
  while (CHB > 1 && fixed + 11ull * (size_t)CHB * 131072ull * 2ull > ws_size)
    CHB >>= 1;

  int* flag = (int*)d_ws;
  u16* WT = (u16*)((char*)d_ws + 64);
  u16* Abf = WT + 8ull * 1048576ull;
  u16* P = Abf + 3ull * (size_t)CHB * 131072ull;
  u16* merged = P + 7ull * (size_t)CHB * 131072ull;

  detect_dtype<<<1, 256, 0, stream>>>(d_in[0], flag);
  cast_w<<<dim3(32, 32, 8), 256, 0, stream>>>(
      d_in[3], d_in[4], d_in[5], d_in[6], d_in[7], d_in[8], d_in[9], d_in[10],
      WT, flag);

  for (int b0 = 0; b0 < 128; b0 += CHB) {
    cast_a<<<dim3(512, 1, 3), 256, 0, stream>>>(
        d_in[0], d_in[1], d_in[2], Abf, b0, CHB, flag);
    proj_mfma<<<dim3(8, CHB, 7), 256, 0, stream>>>(Abf, WT, P, CHB);
    attn_mfma<<<dim3(8, CHB), 256, 0, stream>>>(P, CHB, merged);
    final_mfma<<<dim3(8, CHB), 256, 0, stream>>>(
        merged, WT + 7ull * 1048576ull, d_in[11], d_out, b0, flag);
  }
}